// Round 6
// baseline (262.321 us; speedup 1.0000x reference)
//
#include <hip/hip_runtime.h>
#include <hip/hip_bf16.h>

// Problem constants
#define B_   2
#define N_   512
#define M_   512
#define D_   128    // Dq = Dk = Dv
#define DE_  64
#define H_   8
#define O_   32
#define OUT_ 128
#define DKE_ 192    // Dk + De
#define MP_  516    // padded M for attn_s rows

typedef unsigned short u16;
typedef unsigned int   u32;
typedef short bf16x8 __attribute__((ext_vector_type(8)));
typedef float floatx4 __attribute__((ext_vector_type(4)));

__device__ __forceinline__ u32 pk2bf(float a, float b) {
    __hip_bfloat162 h = __float22bfloat162_rn(make_float2(a, b));
    return *reinterpret_cast<u32*>(&h);
}
__device__ __forceinline__ u16 f2bf(float a) {
    __hip_bfloat16 h = __float2bfloat16(a);
    return *reinterpret_cast<u16*>(&h);
}
// pack 8 fp32 (two float4) -> bf16x8 fragment
__device__ __forceinline__ bf16x8 cvt8(const float4 a, const float4 b) {
    union { u32 u[4]; bf16x8 v; } r;
    r.u[0] = pk2bf(a.x, a.y); r.u[1] = pk2bf(a.z, a.w);
    r.u[2] = pk2bf(b.x, b.y); r.u[3] = pk2bf(b.z, b.w);
    return r.v;
}

// ---------------------------------------------------------------------------
// k_proj, grid = 320 x 256 threads.
// Blocks 0..127   : per 8 (b,n) rows -> qE bf16 [row][h*192+j]  (q.Wq/sqrt, fold Wk)
// Blocks 128..255 : per 8 (b,m) rows -> vP bf16 [b][m>>3][col=h*32+o][m&7]
// Blocks 256..319 : keyF: key in bf16 MFMA-B-fragment order
//                   keyF[b][tl][kk][lane][8], lane=(q<<4)|br,
//                   element j = key[b][tl*16+br][kk*32+q*8+j]
// ---------------------------------------------------------------------------
__global__ __launch_bounds__(256) void k_proj(
    const float* __restrict__ query, const float* __restrict__ Wq,
    const float* __restrict__ Wk,
    const float* __restrict__ value, const float* __restrict__ Wv,
    const float* __restrict__ key,
    u16* __restrict__ qE, u16* __restrict__ vP, u16* __restrict__ keyF)
{
    const int t = threadIdx.x;
    __shared__ float Xs[8][D_];
    __shared__ float qh[8][H_ * O_];

    if (blockIdx.x < 128) {
        const int r0 = blockIdx.x * 8;
        reinterpret_cast<float4*>(&Xs[0][0])[t] =
            reinterpret_cast<const float4*>(query + (size_t)r0 * D_)[t];
        __syncthreads();
        {
            float acc[8] = {0,0,0,0,0,0,0,0};
            const float* wcol = Wq + (t >> 5) * (D_ * O_) + (t & 31);
            for (int k = 0; k < D_; k += 4) {
                const float w0 = wcol[(k+0) * O_];
                const float w1 = wcol[(k+1) * O_];
                const float w2 = wcol[(k+2) * O_];
                const float w3 = wcol[(k+3) * O_];
#pragma unroll
                for (int r = 0; r < 8; ++r) {
                    const float4 x = *reinterpret_cast<const float4*>(&Xs[r][k]);
                    acc[r] += x.x * w0 + x.y * w1 + x.z * w2 + x.w * w3;
                }
            }
#pragma unroll
            for (int r = 0; r < 8; ++r) qh[r][t] = acc[r] * 0.17677669529663687f;
        }
        __syncthreads();

        for (int s = 0; s < 6; ++s) {
            const int hj = t + 256 * s;
            const int h  = hj / DKE_;
            float w[O_];
#pragma unroll
            for (int i = 0; i < O_ / 4; ++i) {
                const float4 x = reinterpret_cast<const float4*>(Wk + (size_t)hj * O_)[i];
                w[4*i] = x.x; w[4*i+1] = x.y; w[4*i+2] = x.z; w[4*i+3] = x.w;
            }
#pragma unroll
            for (int r = 0; r < 8; ++r) {
                const float* qrow = &qh[r][h * O_];
                float a = 0.f;
#pragma unroll
                for (int i = 0; i < O_ / 4; ++i) {
                    const float4 qx = *reinterpret_cast<const float4*>(qrow + 4*i);
                    a += qx.x * w[4*i] + qx.y * w[4*i+1] + qx.z * w[4*i+2] + qx.w * w[4*i+3];
                }
                qE[(size_t)(r0 + r) * (H_ * DKE_) + hj] = f2bf(a);
            }
        }
    } else if (blockIdx.x < 256) {
        const int r0 = (blockIdx.x - 128) * 8;          // global (b,m) row
        reinterpret_cast<float4*>(&Xs[0][0])[t] =
            reinterpret_cast<const float4*>(value + (size_t)r0 * D_)[t];
        __syncthreads();

        float acc[8] = {0,0,0,0,0,0,0,0};
        const float* wcol = Wv + (t >> 5) * (D_ * O_) + (t & 31);
        for (int k = 0; k < D_; k += 4) {
            const float w0 = wcol[(k+0) * O_];
            const float w1 = wcol[(k+1) * O_];
            const float w2 = wcol[(k+2) * O_];
            const float w3 = wcol[(k+3) * O_];
#pragma unroll
            for (int r = 0; r < 8; ++r) {
                const float4 x = *reinterpret_cast<const float4*>(&Xs[r][k]);
                acc[r] += x.x * w0 + x.y * w1 + x.z * w2 + x.w * w3;
            }
        }
        // PV-coalesced bf16 write: vP[b][m0>>3][col=t][0..7] as one 16 B store
        const int bb = r0 >> 9, m0 = r0 & 511;
        union { u32 u[4]; uint4 q; } pk;
        pk.u[0] = pk2bf(acc[0], acc[1]);
        pk.u[1] = pk2bf(acc[2], acc[3]);
        pk.u[2] = pk2bf(acc[4], acc[5]);
        pk.u[3] = pk2bf(acc[6], acc[7]);
        *reinterpret_cast<uint4*>(
            vP + ((((size_t)bb * 64) + (m0 >> 3)) * 256 + t) * 8) = pk.q;
    } else {
        // keyF builder: one block per (b, m-tile)
        const int kb = blockIdx.x - 256;                // 0..63
        const int bb = kb >> 5, tl = kb & 31;
        const int kk = t >> 6, l = t & 63;
        const int br = l & 15, q = l >> 4;
        const float* src = key + ((size_t)bb * M_ + tl * 16 + br) * D_ + kk * 32 + q * 8;
        const float4 f0 = *reinterpret_cast<const float4*>(src);
        const float4 f1 = *reinterpret_cast<const float4*>(src + 4);
        union { bf16x8 v; uint4 u; } r;
        r.v = cvt8(f0, f1);
        *reinterpret_cast<uint4*>(
            keyF + ((((size_t)bb * 32 + tl) * 4 + kk) * 64 + l) * 8) = r.u;
    }
}

// ---------------------------------------------------------------------------
// k_attn: logits + softmax ONLY (PV/MLP split into k_pv so this kernel is a
// uniform edge-streaming phase -> HBM stays busy for its whole duration).
// One block per (b,n), 512 threads = 8 waves, LDS 32.5 KB -> 4 blocks/CU =
// 32 waves/CU. Edge staging: permuted-coalesced global float4 loads (16 full
// lines/instr) -> byte-linear LDS writes (zero conflicts) -> granule-linear
// b128 fragment reads (zero conflicts). keyF fragment loads hoisted to the
// top of each iteration (L2 latency hides under staging VALU).
// Output: attnP fp32 [idx][h][m], coalesced 16 KB store.
// ---------------------------------------------------------------------------
__global__ __launch_bounds__(512, 8) void k_attn(
    const float* __restrict__ edge,
    const u16* __restrict__ qE, const u16* __restrict__ keyF,
    float* __restrict__ attnP)
{
    const int idx  = blockIdx.x;          // b*N + n
    const int b    = idx >> 9;
    const int t    = threadIdx.x;
    const int lane = t & 63;
    const int wv   = t >> 6;              // 0..7

    __shared__ __attribute__((aligned(16))) float attn_s[H_][MP_]; // 16.5 KB
    __shared__ __attribute__((aligned(16))) u16 elds[8][1024];     // 16 KB

    const int br = lane & 15;             // A row (head) / C col (m)
    const int q  = lane >> 4;             // k-quad

    // lane->chunk permutation for edge loads (float4 units within a tile):
    // instruction covers rows 0-15 x one 64B column block = 16 full lines;
    // LDS dest = i*512 + lane*8 bytes (byte-linear -> zero-conflict writes).
    const int base16 = ((lane >> 1) & 15) * 16 + ((lane >> 5) << 1) + (lane & 1);

    // ---- early edge prefetch: first tile for this wave (tl = wv) ----
    const float4* tb = reinterpret_cast<const float4*>(edge + (size_t)idx * (M_ * DE_));
    float4 ef[4];
#pragma unroll
    for (int i = 0; i < 4; ++i)
        ef[i] = tb[wv * 256 + base16 + i * 4];

    // ---- A fragments: lane holds qE[row=br][kk*32 + q*8 + 0..7], rows>=8 zero
    bf16x8 afr[6];
    if (br < 8) {
        const u16* ab = qE + (size_t)idx * (H_ * DKE_) + br * DKE_;
#pragma unroll
        for (int kk = 0; kk < 6; ++kk)
            afr[kk] = *reinterpret_cast<const bf16x8*>(ab + kk * 32 + q * 8);
    } else {
#pragma unroll
        for (int kk = 0; kk < 6; ++kk) afr[kk] = bf16x8{0,0,0,0,0,0,0,0};
    }

    const u16* kfb = keyF + (size_t)b * (32 * 4 * 64 * 8);

    // ---- logits: 4 m-tiles per wave, no barriers inside ----
    for (int it = 0; it < 4; ++it) {
        const int tl = it * 8 + wv;
        // keyF fragment loads issued FIRST (L2 latency hides under staging)
        const u16* kf = kfb + (size_t)tl * 2048 + lane * 8;
        bf16x8 bk0 = *reinterpret_cast<const bf16x8*>(kf);
        bf16x8 bk1 = *reinterpret_cast<const bf16x8*>(kf + 512);
        bf16x8 bk2 = *reinterpret_cast<const bf16x8*>(kf + 1024);
        bf16x8 bk3 = *reinterpret_cast<const bf16x8*>(kf + 1536);
        // stage current tile: byte-linear LDS writes (zero conflicts)
#pragma unroll
        for (int i = 0; i < 4; ++i) {
            uint2 p;
            p.x = pk2bf(ef[i].x, ef[i].y); p.y = pk2bf(ef[i].z, ef[i].w);
            *reinterpret_cast<uint2*>(&elds[wv][i * 256 + lane * 4]) = p;
        }
        // prefetch next tile (same permuted-coalesced pattern)
        if (it < 3) {
#pragma unroll
            for (int i = 0; i < 4; ++i)
                ef[i] = tb[(tl + 8) * 256 + base16 + i * 4];
        }
        // key MFMAs
        floatx4 acc = {0.f, 0.f, 0.f, 0.f};
        acc = __builtin_amdgcn_mfma_f32_16x16x32_bf16(afr[0], bk0, acc, 0, 0, 0);
        acc = __builtin_amdgcn_mfma_f32_16x16x32_bf16(afr[1], bk1, acc, 0, 0, 0);
        acc = __builtin_amdgcn_mfma_f32_16x16x32_bf16(afr[2], bk2, acc, 0, 0, 0);
        acc = __builtin_amdgcn_mfma_f32_16x16x32_bf16(afr[3], bk3, acc, 0, 0, 0);
        // edge MFMAs: granule-linear b128 reads (zero conflicts)
#pragma unroll
        for (int kk = 0; kk < 2; ++kk) {
            const bf16x8 bfr = *reinterpret_cast<const bf16x8*>(&elds[wv][(kk * 64 + lane) * 8]);
            acc = __builtin_amdgcn_mfma_f32_16x16x32_bf16(afr[4 + kk], bfr, acc, 0, 0, 0);
        }
        // C: col=br (m), row=q*4+i = head; only rows 0..7 valid
        if (q < 2) {
#pragma unroll
            for (int i = 0; i < 4; ++i)
                attn_s[q * 4 + i][tl * 16 + br] = acc[i];
        }
    }
    __syncthreads();

    // ---- softmax over m: wave wv owns head wv; 64 lanes x 8 elems ----
    {
        const int h = wv, ml = lane;
        float mx = -3.4e38f;
#pragma unroll
        for (int j = 0; j < 8; ++j) mx = fmaxf(mx, attn_s[h][ml + 64 * j]);
#pragma unroll
        for (int mask = 32; mask >= 1; mask >>= 1) mx = fmaxf(mx, __shfl_xor(mx, mask, 64));
        float sum = 0.f;
#pragma unroll
        for (int j = 0; j < 8; ++j) {
            const int m = ml + 64 * j;
            const float p = __expf(attn_s[h][m] - mx);
            attn_s[h][m] = p;
            sum += p;
        }
#pragma unroll
        for (int mask = 32; mask >= 1; mask >>= 1) sum += __shfl_xor(sum, mask, 64);
        const float inv = 1.f / sum;
#pragma unroll
        for (int j = 0; j < 8; ++j) attn_s[h][ml + 64 * j] *= inv;
    }
    __syncthreads();

    // ---- coalesced fp32 prob store: thread t -> h = t>>6, m0 = (t&63)*8 ----
    {
        const int h = t >> 6, m0 = (t & 63) * 8;
        float* dst = attnP + ((size_t)idx * H_ + h) * M_ + m0;
        *reinterpret_cast<float4*>(dst)     = *reinterpret_cast<const float4*>(&attn_s[h][m0]);
        *reinterpret_cast<float4*>(dst + 4) = *reinterpret_cast<const float4*>(&attn_s[h][m0 + 4]);
    }
}

// ---------------------------------------------------------------------------
// k_pv: PV + projection. One block per (b,n), 256 threads, LDS 18 KB ->
// 8 blocks/CU capacity; blocks stagger naturally, pure L2/VALU streaming.
// ---------------------------------------------------------------------------
__global__ __launch_bounds__(256, 8) void k_pv(
    const float* __restrict__ attnP, const u16* __restrict__ vP,
    const float* __restrict__ Wp, const float* __restrict__ bias,
    float* __restrict__ out)
{
    const int idx = blockIdx.x;           // b*N + n
    const int b   = idx >> 9;
    const int t   = threadIdx.x;

    __shared__ __attribute__((aligned(16))) float attn_ld[H_ * M_]; // 16 KB
    __shared__ float mh_s[256];                                     // 1 KB
    __shared__ float part_s[2][OUT_];                               // 1 KB

    // ---- load probs: 4096 floats, fully linear/coalesced ----
    {
        const float4* src = reinterpret_cast<const float4*>(attnP + (size_t)idx * (H_ * M_));
        float4* dst = reinterpret_cast<float4*>(attn_ld);
#pragma unroll
        for (int i = 0; i < 4; ++i)
            dst[i * 256 + t] = src[i * 256 + t];
    }
    __syncthreads();

    // ---- PV: thread t = col (h,o); coalesced uint4 stream from vP ----
    {
        const int hh = t >> 5;
        const float* wrow = attn_ld + hh * M_;
        const u16* vb = vP + (size_t)b * (64 * 256 * 8) + (size_t)t * 8;
        float a0 = 0.f, a1 = 0.f;
#pragma unroll 8
        for (int j = 0; j < 64; ++j) {
            const uint4 v4 = *reinterpret_cast<const uint4*>(vb + (size_t)j * 2048);
            const float4 w0 = *reinterpret_cast<const float4*>(wrow + j * 8);
            const float4 w1 = *reinterpret_cast<const float4*>(wrow + j * 8 + 4);
            const float v0 = __uint_as_float(v4.x << 16);
            const float v1 = __uint_as_float(v4.x & 0xffff0000u);
            const float v2 = __uint_as_float(v4.y << 16);
            const float v3 = __uint_as_float(v4.y & 0xffff0000u);
            const float v4f = __uint_as_float(v4.z << 16);
            const float v5 = __uint_as_float(v4.z & 0xffff0000u);
            const float v6 = __uint_as_float(v4.w << 16);
            const float v7 = __uint_as_float(v4.w & 0xffff0000u);
            a0 += w0.x * v0 + w0.y * v1 + w0.z * v2 + w0.w * v3;
            a1 += w1.x * v4f + w1.y * v5 + w1.z * v6 + w1.w * v7;
        }
        mh_s[t] = a0 + a1;
    }
    __syncthreads();

    // ---- out[c] = bias[c] + sum_j mh[j] * Wp[j*128 + c] ----
    {
        const int half = t >> 7;
        const int c = t & 127;
        float acc = 0.f;
        const int j0 = half * 128;
#pragma unroll 8
        for (int jj = 0; jj < 128; ++jj)
            acc += mh_s[j0 + jj] * Wp[(size_t)(j0 + jj) * OUT_ + c];
        part_s[half][c] = acc;
    }
    __syncthreads();
    if (t < OUT_)
        out[(size_t)idx * OUT_ + t] = part_s[0][t] + part_s[1][t] + bias[t];
}

// ---------------------------------------------------------------------------
extern "C" void kernel_launch(void* const* d_in, const int* in_sizes, int n_in,
                              void* d_out, int out_size, void* d_ws, size_t ws_size,
                              hipStream_t stream)
{
    const float* query = (const float*)d_in[0];   // [B,N,128]
    const float* key   = (const float*)d_in[1];   // [B,M,128]
    const float* value = (const float*)d_in[2];   // [B,M,128]
    const float* edge  = (const float*)d_in[3];   // [B,N,M,64]
    const float* Wq    = (const float*)d_in[4];   // [8,128,32]
    const float* Wk    = (const float*)d_in[5];   // [8,192,32]
    const float* Wv    = (const float*)d_in[6];   // [8,128,32]
    const float* Wp    = (const float*)d_in[7];   // [8,32,128]
    const float* bias  = (const float*)d_in[8];   // [128]
    float* out = (float*)d_out;                   // [B,N,128] fp32

    float* attnP = (float*)d_ws;                              // 1024*4096*4 = 16 MB
    u16* qE_ws = (u16*)((char*)d_ws + (size_t)B_*N_*H_*M_*4); // 1024*1536*2 = 3 MB
    u16* vP_ws = qE_ws + (size_t)B_ * N_ * H_ * DKE_;         // 512 KB
    u16* kF_ws = vP_ws + (size_t)B_ * 64 * 256 * 8;           // 256 KB

    k_proj<<<320,  256, 0, stream>>>(query, Wq, Wk, value, Wv, key, qE_ws, vP_ws, kF_ws);
    k_attn<<<1024, 512, 0, stream>>>(edge, qE_ws, kF_ws, attnP);
    k_pv  <<<1024, 256, 0, stream>>>(attnP, vP_ws, Wp, bias, out);
}

// Round 9
// 241.963 us; speedup vs baseline: 1.0841x; 1.0841x over previous
//
#include <hip/hip_runtime.h>
#include <hip/hip_bf16.h>

// Problem constants
#define B_   2
#define N_   512
#define M_   512
#define D_   128    // Dq = Dk = Dv
#define DE_  64
#define H_   8
#define O_   32
#define OUT_ 128
#define DKE_ 192    // Dk + De
#define MP_  516    // padded M for attn_s rows

typedef unsigned short u16;
typedef unsigned int   u32;
typedef short bf16x8 __attribute__((ext_vector_type(8)));
typedef float floatx4 __attribute__((ext_vector_type(4)));

__device__ __forceinline__ u32 pk2bf(float a, float b) {
    __hip_bfloat162 h = __float22bfloat162_rn(make_float2(a, b));
    return *reinterpret_cast<u32*>(&h);
}
__device__ __forceinline__ u16 f2bf(float a) {
    __hip_bfloat16 h = __float2bfloat16(a);
    return *reinterpret_cast<u16*>(&h);
}

// ---------------------------------------------------------------------------
// k_proj, grid = 384 x 256 threads.
// Blocks 0..127   : per 8 (b,n) rows -> qh_ws bf16 [idx][h*32+o] (scaled q-proj)
//                   and qE_e bf16 [idx][h*64+j] (edge part of folded Wk)
// Blocks 128..255 : per 8 (b,m) rows -> vP bf16 [b][m>>3][col=h*32+o][m&7]
// Blocks 256..383 : per 8 (b,m) rows -> khb bf16 [b][h][m][o] (key.Wk_key)
// ---------------------------------------------------------------------------
__global__ __launch_bounds__(256) void k_proj(
    const float* __restrict__ query, const float* __restrict__ Wq,
    const float* __restrict__ Wk,
    const float* __restrict__ value, const float* __restrict__ Wv,
    const float* __restrict__ key,
    u16* __restrict__ qh_ws, u16* __restrict__ qE_e,
    u16* __restrict__ vP, u16* __restrict__ khb)
{
    const int t = threadIdx.x;
    __shared__ float Xs[8][D_];
    __shared__ float qh[8][H_ * O_];

    if (blockIdx.x < 128) {
        const int r0 = blockIdx.x * 8;
        reinterpret_cast<float4*>(&Xs[0][0])[t] =
            reinterpret_cast<const float4*>(query + (size_t)r0 * D_)[t];
        __syncthreads();
        {
            float acc[8] = {0,0,0,0,0,0,0,0};
            const float* wcol = Wq + (t >> 5) * (D_ * O_) + (t & 31);
            for (int k = 0; k < D_; k += 4) {
                const float w0 = wcol[(k+0) * O_];
                const float w1 = wcol[(k+1) * O_];
                const float w2 = wcol[(k+2) * O_];
                const float w3 = wcol[(k+3) * O_];
#pragma unroll
                for (int r = 0; r < 8; ++r) {
                    const float4 x = *reinterpret_cast<const float4*>(&Xs[r][k]);
                    acc[r] += x.x * w0 + x.y * w1 + x.z * w2 + x.w * w3;
                }
            }
#pragma unroll
            for (int r = 0; r < 8; ++r) {
                const float v = acc[r] * 0.17677669529663687f;
                qh[r][t] = v;
                qh_ws[(size_t)(r0 + r) * 256 + t] = f2bf(v);
            }
        }
        __syncthreads();

        // edge part of folded Wk: qE_e[row][h*64+j] = sum_o qh[row][h*32+o]*Wk[h][128+j][o]
#pragma unroll
        for (int s = 0; s < 2; ++s) {
            const int hj = t + 256 * s;       // 0..511
            const int h  = hj >> 6, j = hj & 63;
            float w[O_];
#pragma unroll
            for (int i = 0; i < O_ / 4; ++i) {
                const float4 x = reinterpret_cast<const float4*>(
                    Wk + (size_t)(h * DKE_ + 128 + j) * O_)[i];
                w[4*i] = x.x; w[4*i+1] = x.y; w[4*i+2] = x.z; w[4*i+3] = x.w;
            }
#pragma unroll
            for (int r = 0; r < 8; ++r) {
                const float* qrow = &qh[r][h * O_];
                float a = 0.f;
#pragma unroll
                for (int i = 0; i < O_ / 4; ++i) {
                    const float4 qx = *reinterpret_cast<const float4*>(qrow + 4*i);
                    a += qx.x * w[4*i] + qx.y * w[4*i+1] + qx.z * w[4*i+2] + qx.w * w[4*i+3];
                }
                qE_e[(size_t)(r0 + r) * 512 + hj] = f2bf(a);
            }
        }
    } else if (blockIdx.x < 256) {
        const int r0 = (blockIdx.x - 128) * 8;          // global (b,m) row
        reinterpret_cast<float4*>(&Xs[0][0])[t] =
            reinterpret_cast<const float4*>(value + (size_t)r0 * D_)[t];
        __syncthreads();

        float acc[8] = {0,0,0,0,0,0,0,0};
        const float* wcol = Wv + (t >> 5) * (D_ * O_) + (t & 31);
        for (int k = 0; k < D_; k += 4) {
            const float w0 = wcol[(k+0) * O_];
            const float w1 = wcol[(k+1) * O_];
            const float w2 = wcol[(k+2) * O_];
            const float w3 = wcol[(k+3) * O_];
#pragma unroll
            for (int r = 0; r < 8; ++r) {
                const float4 x = *reinterpret_cast<const float4*>(&Xs[r][k]);
                acc[r] += x.x * w0 + x.y * w1 + x.z * w2 + x.w * w3;
            }
        }
        // PV-coalesced bf16 write: vP[b][m0>>3][col=t][0..7] as one 16 B store
        const int bb = r0 >> 9, m0 = r0 & 511;
        union { u32 u[4]; uint4 q; } pk;
        pk.u[0] = pk2bf(acc[0], acc[1]);
        pk.u[1] = pk2bf(acc[2], acc[3]);
        pk.u[2] = pk2bf(acc[4], acc[5]);
        pk.u[3] = pk2bf(acc[6], acc[7]);
        *reinterpret_cast<uint4*>(
            vP + ((((size_t)bb * 64) + (m0 >> 3)) * 256 + t) * 8) = pk.q;
    } else {
        // khb: kh[b][h][m][o] = sum_i key[b,m,i] * Wk[h][i][o]  (i < 128)
        const int r0 = (blockIdx.x - 256) * 8;          // global (b,m) row
        reinterpret_cast<float4*>(&Xs[0][0])[t] =
            reinterpret_cast<const float4*>(key + (size_t)r0 * D_)[t];
        __syncthreads();

        float acc[8] = {0,0,0,0,0,0,0,0};
        const int h = t >> 5, o = t & 31;
        const float* wcol = Wk + (size_t)h * (DKE_ * O_) + o;
        for (int k = 0; k < D_; k += 4) {
            const float w0 = wcol[(k+0) * O_];
            const float w1 = wcol[(k+1) * O_];
            const float w2 = wcol[(k+2) * O_];
            const float w3 = wcol[(k+3) * O_];
#pragma unroll
            for (int r = 0; r < 8; ++r) {
                const float4 x = *reinterpret_cast<const float4*>(&Xs[r][k]);
                acc[r] += x.x * w0 + x.y * w1 + x.z * w2 + x.w * w3;
            }
        }
        const int bb = r0 >> 9, m0 = r0 & 511;
        u16* dst = khb + (((size_t)(bb * 8 + h) * 512) + m0) * 32 + o;
#pragma unroll
        for (int r = 0; r < 8; ++r) dst[(size_t)r * 32] = f2bf(acc[r]);
    }
}

// ---------------------------------------------------------------------------
// k_qk: logits_key[b,h,n,m] = sum_o qh[b,n,h,o] * kh[b,m,h,o]  (K=32, MFMA)
// grid = 512 x 256 (4 waves). Block = (b,h,nc,mc); wave owns n-tile
// ntl = nc*4+wv, loops 8 m-tiles. Output written in k_attn's C-fragment
// order: qkL[idx][mtl][q'(2)][i'(4)][br'(16)] fp32 where h = q'*4+i',
// br' = m_local -> k_attn C-init is 4 scalar loads from one 512 B block.
// ---------------------------------------------------------------------------
__global__ __launch_bounds__(256, 8) void k_qk(
    const u16* __restrict__ qh_ws, const u16* __restrict__ khb,
    float* __restrict__ qkL)
{
    const int bid = blockIdx.x;
    const int b  = bid >> 8, h = (bid >> 5) & 7, nc = (bid >> 2) & 7, mc = bid & 3;
    const int t = threadIdx.x;
    const int lane = t & 63, wv = t >> 6;
    const int br = lane & 15, q = lane >> 4;

    const int ntl = nc * 4 + wv;
    const bf16x8 afr = *reinterpret_cast<const bf16x8*>(
        qh_ws + ((size_t)(b * 512 + ntl * 16 + br)) * 256 + h * 32 + q * 8);
    const u16* kb = khb + ((size_t)(b * 8 + h) * 512) * 32;

#pragma unroll
    for (int mt = 0; mt < 8; ++mt) {
        const int mtl = mc * 8 + mt;
        const bf16x8 bfr = *reinterpret_cast<const bf16x8*>(
            kb + (size_t)(mtl * 16 + br) * 32 + q * 8);
        floatx4 z = {0.f, 0.f, 0.f, 0.f};
        const floatx4 acc = __builtin_amdgcn_mfma_f32_16x16x32_bf16(afr, bfr, z, 0, 0, 0);
        // C row = q*4+i = n_local; col = br = m_local
        float* base = qkL + (size_t)(b * 512 + ntl * 16 + q * 4) * 4096
                    + mtl * 128 + (h >> 2) * 64 + (h & 3) * 16 + br;
#pragma unroll
        for (int i = 0; i < 4; ++i) base[(size_t)i * 4096] = acc[i];
    }
}

// ---------------------------------------------------------------------------
// k_attn: fused logits(edge MFMA + qkL C-init) + softmax + PV + MLP.
// One block per (b,n), 512 threads = 8 waves, LDS 36.5 KB -> 4 blocks/CU.
// Edge staging: permuted-coalesced global float4 loads (16 full lines/instr)
// -> byte-linear LDS writes (zero conflicts) -> granule-linear b128 fragment
// reads (zero conflicts). Key logits arrive precomputed via qkL (2 lines per
// load instr, L2-resident) -> per-iteration chain is stage + 2 MFMAs only.
// MLP reads Wp (128 KB, L2-resident) directly from global (it does NOT fit
// in LDS -- 8*32*128 fp32; round-8 bug was staging 1/8 of it).
// ---------------------------------------------------------------------------
__global__ __launch_bounds__(512, 8) void k_attn(
    const float* __restrict__ edge,
    const u16* __restrict__ qE_e, const float* __restrict__ qkL,
    const u16* __restrict__ vP,
    const float* __restrict__ Wp, const float* __restrict__ bias,
    float* __restrict__ out)
{
    const int idx  = blockIdx.x;          // b*N + n
    const int b    = idx >> 9;
    const int t    = threadIdx.x;
    const int lane = t & 63;
    const int wv   = t >> 6;              // 0..7

    __shared__ __attribute__((aligned(16))) float attn_s[H_][MP_]; // 16.5 KB
    __shared__ __attribute__((aligned(16))) u16 elds[8][1024];     // 16 KB
    __shared__ float mh_s[2][256];                                 // 2 KB
    __shared__ float part_s[4][OUT_];                              // 2 KB

    const int br = lane & 15;             // A row (head) / C col (m)
    const int q  = lane >> 4;             // k-quad

    // lane->chunk permutation for edge loads (float4 units within a tile):
    // instruction covers rows 0-15 x one 64B column block = 16 full lines;
    // LDS dest = i*512 + lane*8 bytes (byte-linear -> zero-conflict writes).
    const int base16 = ((lane >> 1) & 15) * 16 + ((lane >> 5) << 1) + (lane & 1);

    // ---- early edge prefetch: first tile for this wave (tl = wv) ----
    const float4* tb = reinterpret_cast<const float4*>(edge + (size_t)idx * (M_ * DE_));
    float4 ef[4];
#pragma unroll
    for (int i = 0; i < 4; ++i)
        ef[i] = tb[wv * 256 + base16 + i * 4];

    // ---- A fragments (edge only): lane holds qE_e[row=br][kk*32+q*8+..] ----
    bf16x8 afr[2];
    if (br < 8) {
        const u16* ab = qE_e + (size_t)idx * 512 + br * 64;
#pragma unroll
        for (int kk = 0; kk < 2; ++kk)
            afr[kk] = *reinterpret_cast<const bf16x8*>(ab + kk * 32 + q * 8);
    } else {
#pragma unroll
        for (int kk = 0; kk < 2; ++kk) afr[kk] = bf16x8{0,0,0,0,0,0,0,0};
    }

    const float* qb = qkL + (size_t)idx * 4096;

    // ---- logits: 4 m-tiles per wave, no barriers inside ----
    for (int it = 0; it < 4; ++it) {
        const int tl = it * 8 + wv;
        // C-init from precomputed key logits (L2-resident, 2 lines/instr)
        floatx4 acc;
        if (q < 2) {
            const float* qt = qb + tl * 128 + q * 64 + br;
#pragma unroll
            for (int i = 0; i < 4; ++i) acc[i] = qt[i * 16];
        } else {
            acc = floatx4{0.f, 0.f, 0.f, 0.f};
        }
        // stage current tile: byte-linear LDS writes (zero conflicts)
#pragma unroll
        for (int i = 0; i < 4; ++i) {
            uint2 p;
            p.x = pk2bf(ef[i].x, ef[i].y); p.y = pk2bf(ef[i].z, ef[i].w);
            *reinterpret_cast<uint2*>(&elds[wv][i * 256 + lane * 4]) = p;
        }
        // prefetch next tile (same permuted-coalesced pattern)
        if (it < 3) {
#pragma unroll
            for (int i = 0; i < 4; ++i)
                ef[i] = tb[(tl + 8) * 256 + base16 + i * 4];
        }
        // edge MFMAs: granule-linear b128 reads (zero conflicts)
#pragma unroll
        for (int kk = 0; kk < 2; ++kk) {
            const bf16x8 bfr = *reinterpret_cast<const bf16x8*>(&elds[wv][(kk * 64 + lane) * 8]);
            acc = __builtin_amdgcn_mfma_f32_16x16x32_bf16(afr[kk], bfr, acc, 0, 0, 0);
        }
        // C: col=br (m), row=q*4+i = head; only rows 0..7 valid
        if (q < 2) {
#pragma unroll
            for (int i = 0; i < 4; ++i)
                attn_s[q * 4 + i][tl * 16 + br] = acc[i];
        }
    }
    __syncthreads();

    // ---- softmax over m: wave wv owns head wv; 64 lanes x 8 elems ----
    {
        const int h = wv, ml = lane;
        float mx = -3.4e38f;
#pragma unroll
        for (int j = 0; j < 8; ++j) mx = fmaxf(mx, attn_s[h][ml + 64 * j]);
#pragma unroll
        for (int mask = 32; mask >= 1; mask >>= 1) mx = fmaxf(mx, __shfl_xor(mx, mask, 64));
        float sum = 0.f;
#pragma unroll
        for (int j = 0; j < 8; ++j) {
            const int m = ml + 64 * j;
            const float p = __expf(attn_s[h][m] - mx);
            attn_s[h][m] = p;
            sum += p;
        }
#pragma unroll
        for (int mask = 32; mask >= 1; mask >>= 1) sum += __shfl_xor(sum, mask, 64);
        const float inv = 1.f / sum;
#pragma unroll
        for (int j = 0; j < 8; ++j) attn_s[h][ml + 64 * j] *= inv;
    }
    __syncthreads();

    // ---- PV: col tt=(h,o), m in halves; coalesced uint4 stream from vP ----
    {
        const int tt = t & 255, half = t >> 8, hh = tt >> 5;
        const u16* vb = vP + (size_t)b * (64 * 256 * 8)
                      + ((size_t)(half * 32) * 256 + tt) * 8;
        const int mbase = half * 256;
        float a0 = 0.f, a1 = 0.f;
#pragma unroll 8
        for (int j = 0; j < 32; ++j) {
            const uint4 v4 = *reinterpret_cast<const uint4*>(vb + (size_t)j * 2048);
            const int m0 = mbase + j * 8;
            const float4 w0 = *reinterpret_cast<const float4*>(&attn_s[hh][m0]);
            const float4 w1 = *reinterpret_cast<const float4*>(&attn_s[hh][m0 + 4]);
            const float v0 = __uint_as_float(v4.x << 16);
            const float v1 = __uint_as_float(v4.x & 0xffff0000u);
            const float v2 = __uint_as_float(v4.y << 16);
            const float v3 = __uint_as_float(v4.y & 0xffff0000u);
            const float v4f = __uint_as_float(v4.z << 16);
            const float v5 = __uint_as_float(v4.z & 0xffff0000u);
            const float v6 = __uint_as_float(v4.w << 16);
            const float v7 = __uint_as_float(v4.w & 0xffff0000u);
            a0 += w0.x * v0 + w0.y * v1 + w0.z * v2 + w0.w * v3;
            a1 += w1.x * v4f + w1.y * v5 + w1.z * v6 + w1.w * v7;
        }
        mh_s[half][tt] = a0 + a1;
    }
    __syncthreads();

    // ---- out[c] = bias[c] + sum_j mh[j] * Wp[j*128 + c], 4 j-segments ----
    {
        const int seg = t >> 7, c = t & 127;
        const int j0 = seg * 64;
        float acc = 0.f;
#pragma unroll 8
        for (int jj = 0; jj < 64; ++jj) {
            const int j = j0 + jj;
            acc += (mh_s[0][j] + mh_s[1][j]) * Wp[(size_t)j * OUT_ + c];
        }
        part_s[seg][c] = acc;
    }
    __syncthreads();
    if (t < OUT_)
        out[(size_t)idx * OUT_ + t] = part_s[0][t] + part_s[1][t]
                                    + part_s[2][t] + part_s[3][t] + bias[t];
}

// ---------------------------------------------------------------------------
extern "C" void kernel_launch(void* const* d_in, const int* in_sizes, int n_in,
                              void* d_out, int out_size, void* d_ws, size_t ws_size,
                              hipStream_t stream)
{
    const float* query = (const float*)d_in[0];   // [B,N,128]
    const float* key   = (const float*)d_in[1];   // [B,M,128]
    const float* value = (const float*)d_in[2];   // [B,M,128]
    const float* edge  = (const float*)d_in[3];   // [B,N,M,64]
    const float* Wq    = (const float*)d_in[4];   // [8,128,32]
    const float* Wk    = (const float*)d_in[5];   // [8,192,32]
    const float* Wv    = (const float*)d_in[6];   // [8,128,32]
    const float* Wp    = (const float*)d_in[7];   // [8,32,128]
    const float* bias  = (const float*)d_in[8];   // [128]
    float* out = (float*)d_out;                   // [B,N,128] fp32

    float* qkL  = (float*)d_ws;                               // 1024*4096*4 = 16 MB
    u16* qh_ws  = (u16*)((char*)d_ws + (size_t)16 * 1024 * 1024);   // 512 KB
    u16* qEe_ws = qh_ws + (size_t)1024 * 256;                 // 1 MB
    u16* vP_ws  = qEe_ws + (size_t)1024 * 512;                // 512 KB
    u16* khb_ws = vP_ws + (size_t)B_ * 64 * 256 * 8;          // 512 KB

    k_proj<<<384,  256, 0, stream>>>(query, Wq, Wk, value, Wv, key,
                                     qh_ws, qEe_ws, vP_ws, khb_ws);
    k_qk  <<<512,  256, 0, stream>>>(qh_ws, khb_ws, qkL);
    k_attn<<<1024, 512, 0, stream>>>(edge, qEe_ws, qkL, vP_ws, Wp, bias, out);
}